// Round 7
// baseline (325.231 us; speedup 1.0000x reference)
//
#include <hip/hip_runtime.h>
#include <stdint.h>

// ---------------------------------------------------------------------------
// Social LSTM model, bf16 MFMA: A hi-only (RNE), B hi-only (RNE).
// R7: enc occupancy unlock. R6's x-proj-into-MFMA dropped natural footprint
//     64->44 arch VGPR (+16 acc = ~60 unified). An 8-wave/SIMD budget is 64
//     regs -> NOW fits naturally (R3/R5 spilled because footprint was ~80).
//     Changes vs R6: (a) enc launch_bounds(256,8) -> 8 blocks/CU capacity;
//     (b) drop persistent h[4] regs -- final C-write re-reads bf16 h-plane
//     (R5-proven bit-identical: dec RNE-rounds h0; rne idempotent, max-pool
//     monotone). Footprint ~40+16=56 <= 64.
//   enc: 12 MFMA/step ([h|x0,x1,1] K-extension), ping-pong hi-only h planes.
//   prep: 49 blocks; packs B-frags + dec bias; block 48 = prefix scan.
//   dec: v8 (R2): 256x512, in-register cell, 1 barrier/step. Untouched.
// Spill tripwire (R3/R5 lesson): VGPR_Count small + FETCH >> 4MB = scratch
// spill -> revert bounds to (256,4).
// ---------------------------------------------------------------------------

#define T_SEQ 50
#define PRED_STEPS 30
#define NMAX 16

typedef float v2f __attribute__((ext_vector_type(2)));
typedef float v4f __attribute__((ext_vector_type(4)));
typedef short v8s __attribute__((ext_vector_type(8)));

#define L2E 1.44269504f
#define L2E2 2.88539008f

// ws layout (float offsets)
static constexpr size_t OFF_AEMB  = 0;          // 2048*64
static constexpr size_t OFF_NENC  = 131072;     // 32768*64
static constexpr size_t OFF_IDX   = 2228224;    // 32768 ints + 1 counter
static constexpr size_t OFF_PACKA = 2490368;    // 8192 floats (32 KB pack)
static constexpr size_t OFF_PACKN = 2498560;    // 8192 floats
static constexpr size_t OFF_WDP   = 2506752;    // 32768 floats (128 KB pack)
static constexpr size_t OFF_WDB   = 2539520;    // 512 floats fused dec bias

__device__ __forceinline__ float frcp(float x) { return __builtin_amdgcn_rcpf(x); }
#if __has_builtin(__builtin_amdgcn_exp2f)
__device__ __forceinline__ float fexp2(float x) { return __builtin_amdgcn_exp2f(x); }
#else
__device__ __forceinline__ float fexp2(float x) { return exp2f(x); }
#endif
__device__ __forceinline__ unsigned bf16rne(float f) {
  unsigned u = __float_as_uint(f);
  u += 0x7fff + ((u >> 16) & 1);
  return u >> 16;
}
__device__ __forceinline__ v4f mfma16(v8s a, v8s b, v4f c) {
  return __builtin_amdgcn_mfma_f32_16x16x32_bf16(a, b, c, 0, 0, 0);
}

// Shared-rcp LSTM cell. Gates PRE-SCALED: i,f,o by log2e; g by 2*log2e.
__device__ __forceinline__ float cell_update(float iv, float fv, float gv,
                                             float ov, float& cref) {
  float ef = fexp2(-fv);
  float ei = fexp2(-iv);
  float eg = fexp2(-gv);
  float t1 = (1.f + ei) * (1.f + eg);
  float rD = frcp((1.f + ef) * t1);
  float sf = t1 * rD;
  float u  = (1.f - eg) * ((1.f + ef) * rD);
  float cn = fmaf(sf, cref, u);
  cref = cn;
  float eo = fexp2(-ov);
  float ec = fexp2(fminf(-L2E2 * cn, 60.f));
  return (1.f - ec) * frcp((1.f + eo) * (1.f + ec));
}

// pack 8 consecutive scaled floats -> hi-only RNE bf16x8 (one uint4)
__device__ __forceinline__ uint4 pack8(const float* __restrict__ p, float gs) {
  float4 w0 = *(const float4*)p;
  float4 w1 = *(const float4*)(p + 4);
  uint4 o;
  o.x = bf16rne(w0.x * gs) | (bf16rne(w0.y * gs) << 16);
  o.y = bf16rne(w0.z * gs) | (bf16rne(w0.w * gs) << 16);
  o.z = bf16rne(w1.x * gs) | (bf16rne(w1.y * gs) << 16);
  o.w = bf16rne(w1.z * gs) | (bf16rne(w1.w * gs) << 16);
  return o;
}
__device__ __forceinline__ uint4 pack8sum(const float* __restrict__ pa,
                                          const float* __restrict__ pb, float gs) {
  float4 a0 = *(const float4*)pa, a1 = *(const float4*)(pa + 4);
  float4 b0 = *(const float4*)pb, b1 = *(const float4*)(pb + 4);
  uint4 o;
  o.x = bf16rne((a0.x + b0.x) * gs) | (bf16rne((a0.y + b0.y) * gs) << 16);
  o.y = bf16rne((a0.z + b0.z) * gs) | (bf16rne((a0.w + b0.w) * gs) << 16);
  o.z = bf16rne((a1.x + b1.x) * gs) | (bf16rne((a1.y + b1.y) * gs) << 16);
  o.w = bf16rne((a1.z + b1.z) * gs) | (bf16rne((a1.w + b1.w) * gs) << 16);
  return o;
}
__device__ __forceinline__ v8s as_v8s(uint4 u) {
  union { uint4 u4; v8s s8; } cv; cv.u4 = u; return cv.s8;
}

// ---------------------------------------------------------------------------
// Merged prep, 49 blocks x 256. Block 48: deterministic compaction scan.
// ---------------------------------------------------------------------------
__global__ void prep_kernel(const float* __restrict__ Whh_a, const float* __restrict__ Whh_n,
                            const float* __restrict__ Wih_d, const float* __restrict__ Whh_d,
                            const float* __restrict__ bih_d, const float* __restrict__ bhh_d,
                            const int* __restrict__ cnts,
                            uint4* __restrict__ packA, uint4* __restrict__ packN,
                            uint4* __restrict__ packD, float* __restrict__ bd,
                            int* __restrict__ idxb) {
  const int b = blockIdx.x;
  if (b == 48) {
    // two-level inclusive scan of clamped counts; 256 thr x 8 entries.
    __shared__ int wsum[4];
    const int t = threadIdx.x, lane = t & 63, w = t >> 6;
    int c[8], tot = 0;
#pragma unroll
    for (int j = 0; j < 8; ++j) {
      int v = cnts[t * 8 + j];
      c[j] = v < 0 ? 0 : (v > NMAX ? NMAX : v);
      tot += c[j];
    }
    int inc = tot;
#pragma unroll
    for (int off = 1; off < 64; off <<= 1) {
      int v = __shfl_up(inc, off, 64);
      if (lane >= off) inc += v;
    }
    if (lane == 63) wsum[w] = inc;
    __syncthreads();
    int wbase = 0;
    for (int k = 0; k < w; ++k) wbase += wsum[k];
    int pos = wbase + inc - tot;  // exclusive prefix
#pragma unroll
    for (int j = 0; j < 8; ++j)
      for (int k = 0; k < c[j]; ++k) idxb[pos++] = (t * 8 + j) * NMAX + k;
    if (t == 0) {
      int Nv = wsum[0] + wsum[1] + wsum[2] + wsum[3];
      idxb[32768] = Nv;
      int end = (Nv + 15) & ~15;
      for (int i = Nv; i < end; ++i) idxb[i] = -1;  // tail block guard
    }
    return;
  }
  if (b < 16) {
    const int which = b >> 3;
    const float* Whh = which ? Whh_n : Whh_a;
    uint4* dst = which ? packN : packA;
    const int idx = (b & 7) * 256 + threadIdx.x;   // 0..2047
    const int lane = idx & 63, c = idx >> 6;       // c 0..31
    const int kh = c & 1, g = (c >> 1) & 3, w = c >> 3;
    const float gs = (g == 2) ? L2E2 : L2E;
    const int row = g * 64 + 16 * w + (lane & 15);
    const int kb = kh * 32 + (lane >> 4) * 8;
    dst[c * 64 + lane] = pack8(Whh + row * 64 + kb, gs);
  } else {
    const int idx = (b - 16) * 256 + threadIdx.x;  // 0..8191
    const int lane = idx & 63, c = idx >> 6;       // c 0..127
    const int kh = c & 3, i = (c >> 2) & 1, wv = c >> 3;
    const int g = wv & 3, q = wv >> 2;
    const float gs = (g == 2) ? L2E2 : L2E;
    const int ju = q * 32 + i * 16 + (lane & 15);
    const int row = g * 128 + ju;
    const int kb = kh * 32 + (lane >> 4) * 8;
    packD[c * 64 + lane] = pack8sum(Wih_d + row * 128 + kb, Whh_d + row * 128 + kb, gs);
    if (b < 18) {
      int iB = (b - 16) * 256 + threadIdx.x;       // 0..511
      float s = ((iB >> 7) == 2) ? L2E2 : L2E;
      bd[iB] = (bih_d[iB] + bhh_d[iB]) * s;
    }
  }
}

// ---------------------------------------------------------------------------
// Encoder. Blocks [0,2048) neighbour (compacted; dead tail exits),
// [2048,2176) agent; 256 thr = 4 waves. Ping-pong h planes (halfwords,
// HI-ONLY): buf b at base b*1152; row stride 72.
// 12 MFMA/step: x-projection rides a K-extension block (lanes ks==0 carry
// bf16(x0),bf16(x1),1.0; B2[g] carries bf16(wi0,wi1,bias), gs-folded).
// launch_bounds(256,8): footprint ~40 arch + 16 acc = 56 <= 64-reg budget.
// ---------------------------------------------------------------------------
__global__ __launch_bounds__(256, 8) void enc_mfma_kernel(
    const float* __restrict__ xA, const float* __restrict__ xN,
    const v8s* __restrict__ packA, const v8s* __restrict__ packN,
    const float* __restrict__ Wih_a, const float* __restrict__ bih_a, const float* __restrict__ bhh_a,
    const float* __restrict__ Wih_n, const float* __restrict__ bih_n, const float* __restrict__ bhh_n,
    const int* __restrict__ idxb,
    float* __restrict__ outA, float* __restrict__ outN) {
  __shared__ unsigned short hph[2304];  // 2 ping-pong hi-planes
  __shared__ unsigned xbf[800];         // [seq][t] bf16(x0)|bf16(x1)<<16
  __shared__ int sidx[16];
  const int tid = threadIdx.x, lane = tid & 63, wv = tid >> 6;
  const int nb = blockIdx.x;
  const bool isA = nb >= 2048;
  const int s0 = (isA ? nb - 2048 : nb) * 16;

  // dead neighbour blocks: everything past the compacted valid prefix
  if (!isA && s0 >= idxb[32768]) return;

  const float* xsrc = isA ? xA : xN;
  const v8s* pk = isA ? packA : packN;
  const float* Wih = isA ? Wih_a : Wih_n;
  const float* bih = isA ? bih_a : bih_n;
  const float* bhh = isA ? bhh_a : bhh_n;
  float* outp = isA ? outA : outN;

  // coalesced B-frag load (hi-only): chunk = wv*8+g*2+kh
  v8s B[4][2];
#pragma unroll
  for (int g = 0; g < 4; ++g)
#pragma unroll
    for (int kh = 0; kh < 2; ++kh)
      B[g][kh] = pk[(wv * 8 + g * 2 + kh) * 64 + lane];

  // B2[g]: x-projection fragment. Lanes ks==0 (lane<16): k-slot0 = wi0,
  // slot1 = wi1, slot2 = bias (all gs-scaled bf16); other lanes zero.
  v8s B2[4];
#pragma unroll
  for (int g = 0; g < 4; ++g) {
    uint4 u = {0u, 0u, 0u, 0u};
    if ((lane >> 4) == 0) {
      const float gs = (g == 2) ? L2E2 : L2E;
      const int ui = g * 64 + 16 * wv + (lane & 15);
      u.x = bf16rne(Wih[2 * ui] * gs) | (bf16rne(Wih[2 * ui + 1] * gs) << 16);
      u.y = bf16rne((bih[ui] + bhh[ui]) * gs);
    }
    B2[g] = as_v8s(u);
  }

  const int jc = lane & 15, qc = lane >> 4;  // C roles: unit col, seq quad
  const int c16 = 16 * wv + jc;

  // seq index table + zero buf0, then gather-stage x as bf16 pairs
  if (tid < 16) sidx[tid] = isA ? (s0 + tid) : idxb[s0 + tid];
  for (int i = tid; i < 576; i += 256) ((unsigned*)hph)[i] = 0;
  __syncthreads();  // sidx + hph-zero visible
  for (int i = tid; i < 400; i += 256) {
    int slot = i / 25, j = i - slot * 25;  // 25 float4 per seq
    int sq = sidx[slot];
    float4 v = ((const float4*)(xsrc + (size_t)(sq < 0 ? 0 : sq) * 100))[j];
    xbf[slot * 50 + 2 * j]     = bf16rne(v.x) | (bf16rne(v.y) << 16);
    xbf[slot * 50 + 2 * j + 1] = bf16rne(v.z) | (bf16rne(v.w) << 16);
  }
  __syncthreads();

  const int ms = lane & 15, ks = lane >> 4;  // A roles: seq row, k-quad
  const v4f vzero = {0.f, 0.f, 0.f, 0.f};
  float cst[4] = {0.f, 0.f, 0.f, 0.f};

  auto enc_step = [&](int t, int rb, int wb) {
    // A2: x-block (lanes ks==0: bf16(x0),bf16(x1),1.0; rest zero)
    uint4 a2u;
    a2u.x = (ks == 0) ? xbf[ms * 50 + t] : 0u;
    a2u.y = (ks == 0) ? 0x3f80u : 0u;   // bf16(1.0) in slot 2
    a2u.z = 0u; a2u.w = 0u;
    v8s A2 = as_v8s(a2u);

    v4f a4[4];
#pragma unroll
    for (int g = 0; g < 4; ++g)
      a4[g] = mfma16(A2, B2[g], vzero);   // wi0*x0 + wi1*x1 + bias

    // h @ Whh^T, A hi-only: 8 MFMA
#pragma unroll
    for (int kh = 0; kh < 2; ++kh) {
      v8s Ahi = *(const __shared__ v8s*)&hph[rb + ms * 72 + kh * 32 + ks * 8];
#pragma unroll
      for (int g = 0; g < 4; ++g)
        a4[g] = mfma16(Ahi, B[g][kh], a4[g]);
    }

    // pointwise + RNE bf16 h-store into the OTHER buffer
#pragma unroll
    for (int r = 0; r < 4; ++r) {
      float h = cell_update(a4[0][r], a4[1][r], a4[2][r], a4[3][r], cst[r]);
      hph[wb + (qc * 4 + r) * 72 + c16] = (unsigned short)bf16rne(h);
    }
    __syncthreads();
  };

  for (int t2 = 0; t2 < T_SEQ; t2 += 2) {
    enc_step(t2 + 0, 0, 1152);
    enc_step(t2 + 1, 1152, 0);
  }

  // final h in buffer 0 (t=49 wrote wb=0); widen bf16 -> fp32. Bit-identical
  // downstream: dec staging RNE-rounds h0 (idempotent, monotone max-pool).
#pragma unroll
  for (int r = 0; r < 4; ++r) {
    int sq = sidx[qc * 4 + r];
    if (sq >= 0) {
      unsigned hs = hph[(qc * 4 + r) * 72 + c16];
      outp[(size_t)sq * 64 + c16] = __uint_as_float(hs << 16);
    }
  }
}

// ---------------------------------------------------------------------------
// Decoder v8. 256 blocks x 512 thr (8 waves), 8 seqs/block.
// Wave wv owns units [wv*16, wv*16+16) and ALL 4 gates: 16 MFMA/step.
// Cell update fully in-register; ping-pong hph -> ONE barrier per step.
// Pred partials -> pall, combined once at the end.
// ---------------------------------------------------------------------------
__global__ __launch_bounds__(512, 2) void dec_mfma_kernel(
    const v8s* __restrict__ pkd, const float* __restrict__ bd,
    const float* __restrict__ aemb, const float* __restrict__ nenc,
    const int* __restrict__ cnts, const float* __restrict__ Wpos,
    const float* __restrict__ bpos, float* __restrict__ out) {
  __shared__ unsigned short hph[2][2176];  // 16 rows x stride 136, ping-pong
  __shared__ float pall[3840];             // [t][wv][s][c] = t*128+wv*16+s*2+c
  const int tid = threadIdx.x, lane = tid & 63, wv = tid >> 6;  // wv 0..7
  const int jc = lane & 15, qc = lane >> 4;
  const int s0 = blockIdx.x * 8;

  // B-frags: gate g, unit tile wv, k-half kh (prep chunk layout).
  v8s B[4][4];
  float bs[4];
#pragma unroll
  for (int g = 0; g < 4; ++g) {
#pragma unroll
    for (int kh = 0; kh < 4; ++kh)
      B[g][kh] = pkd[(((wv >> 1) * 4 + g) * 8 + (wv & 1) * 4 + kh) * 64 + lane];
    bs[g] = bd[g * 128 + wv * 16 + jc];
  }
  const float wp0 = Wpos[wv * 16 + jc];
  const float wp1 = Wpos[128 + wv * 16 + jc];
  const float bp0 = bpos[0], bp1 = bpos[1];

  // zero both hph buffers (rows 8..15 stay zero forever)
  for (int i = tid; i < 2176; i += 512) ((unsigned*)hph)[i] = 0;
  __syncthreads();

  // stage h0 rows 0..7 into buf0 (fused hmax; only cnt neighbour rows read)
  for (int i = tid; i < 1024; i += 512) {
    int row = i >> 7, unit = i & 127;
    float v;
    if (unit < 64) {
      v = aemb[(size_t)(s0 + row) * 64 + unit];
    } else {
      int cnt = cnts[s0 + row];
      cnt = cnt < 0 ? 0 : (cnt > NMAX ? NMAX : cnt);
      float m = -1e30f;
      for (int n = 0; n < cnt; ++n)
        m = fmaxf(m, nenc[((size_t)((s0 + row) * NMAX + n)) * 64 + (unit - 64)]);
      v = (cnt > 0) ? m : 0.f;
    }
    hph[0][row * 136 + unit] = (unsigned short)bf16rne(v);
  }
  float cst[4] = {0.f, 0.f, 0.f, 0.f};
  __syncthreads();

  for (int t = 0; t < PRED_STEPS; ++t) {
    const int rb = t & 1, wb = rb ^ 1;
    v4f acc[4];
#pragma unroll
    for (int g = 0; g < 4; ++g)
      acc[g] = (v4f){bs[g], bs[g], bs[g], bs[g]};
#pragma unroll
    for (int kh = 0; kh < 4; ++kh) {
      v8s Ahi = *(const __shared__ v8s*)&hph[rb][jc * 136 + kh * 32 + qc * 8];
#pragma unroll
      for (int g = 0; g < 4; ++g)
        acc[g] = mfma16(Ahi, B[g][kh], acc[g]);
    }

    // in-register cell: rows qc*4+r; valid seqs are qc<2 (rows 8..15 are
    // zero-h -> bias-only gates, finite garbage, never stored)
    float hr[4];
#pragma unroll
    for (int r = 0; r < 4; ++r)
      hr[r] = cell_update(acc[0][r], acc[1][r], acc[2][r], acc[3][r], cst[r]);

    if (qc < 2) {
#pragma unroll
      for (int r = 0; r < 4; ++r)
        hph[wb][(qc * 4 + r) * 136 + wv * 16 + jc] =
            (unsigned short)bf16rne(hr[r]);
    }

    // pred partials: reduce over jc (16 lanes) within each qc group
    float pr0[4], pr1[4];
#pragma unroll
    for (int r = 0; r < 4; ++r) { pr0[r] = hr[r] * wp0; pr1[r] = hr[r] * wp1; }
#pragma unroll
    for (int off = 1; off < 16; off <<= 1) {
#pragma unroll
      for (int r = 0; r < 4; ++r) {
        pr0[r] += __shfl_xor(pr0[r], off, 64);
        pr1[r] += __shfl_xor(pr1[r], off, 64);
      }
    }
    if (jc == 0 && qc < 2) {
#pragma unroll
      for (int r = 0; r < 4; ++r) {
        int s = qc * 4 + r;
        pall[t * 128 + wv * 16 + s * 2 + 0] = pr0[r];
        pall[t * 128 + wv * 16 + s * 2 + 1] = pr1[r];
      }
    }
    __syncthreads();  // single barrier: hph[wb] + (eventually) pall visible
  }

  // combine pred partials: 480 outputs, sum over 8 waves
  if (tid < 480) {
    int s = tid / 60, r60 = tid - s * 60;
    int t = r60 >> 1, c = r60 & 1;
    float a = c ? bp1 : bp0;
#pragma unroll
    for (int w = 0; w < 8; ++w)
      a += pall[t * 128 + w * 16 + s * 2 + c];
    out[(size_t)(s0 + s) * 60 + r60] = a;
  }
}

extern "C" void kernel_launch(void* const* d_in, const int* in_sizes, int n_in,
                              void* d_out, int out_size, void* d_ws, size_t ws_size,
                              hipStream_t stream) {
  (void)in_sizes; (void)n_in; (void)out_size; (void)ws_size;
  const float* xA    = (const float*)d_in[0];
  const float* xN    = (const float*)d_in[1];
  const int*   cnts  = (const int*)d_in[2];
  const float* Wih_a = (const float*)d_in[3];
  const float* Whh_a = (const float*)d_in[4];
  const float* bih_a = (const float*)d_in[5];
  const float* bhh_a = (const float*)d_in[6];
  const float* Wih_n = (const float*)d_in[7];
  const float* Whh_n = (const float*)d_in[8];
  const float* bih_n = (const float*)d_in[9];
  const float* bhh_n = (const float*)d_in[10];
  const float* Wih_d = (const float*)d_in[11];
  const float* Whh_d = (const float*)d_in[12];
  const float* bih_d = (const float*)d_in[13];
  const float* bhh_d = (const float*)d_in[14];
  const float* Wpos  = (const float*)d_in[15];
  const float* bpos  = (const float*)d_in[16];
  float* out = (float*)d_out;
  float* wsf = (float*)d_ws;
  int* idxb = (int*)(wsf + OFF_IDX);

  prep_kernel<<<49, 256, 0, stream>>>(Whh_a, Whh_n, Wih_d, Whh_d, bih_d, bhh_d,
                                      cnts,
                                      (uint4*)(wsf + OFF_PACKA),
                                      (uint4*)(wsf + OFF_PACKN),
                                      (uint4*)(wsf + OFF_WDP), wsf + OFF_WDB,
                                      idxb);
  enc_mfma_kernel<<<2176, 256, 0, stream>>>(
      xA, xN,
      (const v8s*)(wsf + OFF_PACKA), (const v8s*)(wsf + OFF_PACKN),
      Wih_a, bih_a, bhh_a, Wih_n, bih_n, bhh_n, idxb,
      wsf + OFF_AEMB, wsf + OFF_NENC);
  dec_mfma_kernel<<<256, 512, 0, stream>>>(
      (const v8s*)(wsf + OFF_WDP), wsf + OFF_WDB,
      wsf + OFF_AEMB, wsf + OFF_NENC, cnts,
      Wpos, bpos, out);
}

// Round 9
// 245.757 us; speedup vs baseline: 1.3234x; 1.3234x over previous
//
#include <hip/hip_runtime.h>
#include <stdint.h>

// ---------------------------------------------------------------------------
// Social LSTM model, bf16 MFMA: A hi-only (RNE), B hi-only (RNE).
// R8 (resubmit; R8 bench was an infra failure, source re-audited clean).
//     enc 2-group ILP. (256,4) is FINAL (R3/R5/R7: any higher min-wave
//     bound spills; 64-reg budget incl. acc can't hold the kernel).
//     Each block runs TWO independent 16-seq groups (32 seqs): two
//     independent MFMA->cell chains per wave fill latency bubbles (ILP
//     replaces the TLP launch_bounds can't buy), barriers/seq halve, and
//     live blocks 1152->640 <= 1024 co-resident -> one residency round.
//     Reg cost +16 acc + 8 cst ~= 95 total << 128 budget: no spill risk.
//   enc: 24 MFMA/step (2 groups x [h|x0,x1,1] K-extension), ping-pong
//        hi-only h planes per group; final C-write re-reads bf16 h-plane
//        (R5/R7-verified bit-identical).
//   prep: 49 blocks; packs B-frags + dec bias; block 48 = prefix scan,
//        idx tail padded to 32-boundary.
//   dec: v8 (R2): 256x512, in-register cell, 1 barrier/step. Untouched.
// Accuracy ledger: absmax sat at 2^-10 since R1; grouping changes nothing
// arithmetically (same per-seq math, same order).
// ---------------------------------------------------------------------------

#define T_SEQ 50
#define PRED_STEPS 30
#define NMAX 16

typedef float v2f __attribute__((ext_vector_type(2)));
typedef float v4f __attribute__((ext_vector_type(4)));
typedef short v8s __attribute__((ext_vector_type(8)));

#define L2E 1.44269504f
#define L2E2 2.88539008f

// ws layout (float offsets)
static constexpr size_t OFF_AEMB  = 0;          // 2048*64
static constexpr size_t OFF_NENC  = 131072;     // 32768*64
static constexpr size_t OFF_IDX   = 2228224;    // 32768 ints + 1 counter
static constexpr size_t OFF_PACKA = 2490368;    // 8192 floats (32 KB pack)
static constexpr size_t OFF_PACKN = 2498560;    // 8192 floats
static constexpr size_t OFF_WDP   = 2506752;    // 32768 floats (128 KB pack)
static constexpr size_t OFF_WDB   = 2539520;    // 512 floats fused dec bias

__device__ __forceinline__ float frcp(float x) { return __builtin_amdgcn_rcpf(x); }
#if __has_builtin(__builtin_amdgcn_exp2f)
__device__ __forceinline__ float fexp2(float x) { return __builtin_amdgcn_exp2f(x); }
#else
__device__ __forceinline__ float fexp2(float x) { return exp2f(x); }
#endif
__device__ __forceinline__ unsigned bf16rne(float f) {
  unsigned u = __float_as_uint(f);
  u += 0x7fff + ((u >> 16) & 1);
  return u >> 16;
}
__device__ __forceinline__ v4f mfma16(v8s a, v8s b, v4f c) {
  return __builtin_amdgcn_mfma_f32_16x16x32_bf16(a, b, c, 0, 0, 0);
}

// Shared-rcp LSTM cell. Gates PRE-SCALED: i,f,o by log2e; g by 2*log2e.
__device__ __forceinline__ float cell_update(float iv, float fv, float gv,
                                             float ov, float& cref) {
  float ef = fexp2(-fv);
  float ei = fexp2(-iv);
  float eg = fexp2(-gv);
  float t1 = (1.f + ei) * (1.f + eg);
  float rD = frcp((1.f + ef) * t1);
  float sf = t1 * rD;
  float u  = (1.f - eg) * ((1.f + ef) * rD);
  float cn = fmaf(sf, cref, u);
  cref = cn;
  float eo = fexp2(-ov);
  float ec = fexp2(fminf(-L2E2 * cn, 60.f));
  return (1.f - ec) * frcp((1.f + eo) * (1.f + ec));
}

// pack 8 consecutive scaled floats -> hi-only RNE bf16x8 (one uint4)
__device__ __forceinline__ uint4 pack8(const float* __restrict__ p, float gs) {
  float4 w0 = *(const float4*)p;
  float4 w1 = *(const float4*)(p + 4);
  uint4 o;
  o.x = bf16rne(w0.x * gs) | (bf16rne(w0.y * gs) << 16);
  o.y = bf16rne(w0.z * gs) | (bf16rne(w0.w * gs) << 16);
  o.z = bf16rne(w1.x * gs) | (bf16rne(w1.y * gs) << 16);
  o.w = bf16rne(w1.z * gs) | (bf16rne(w1.w * gs) << 16);
  return o;
}
__device__ __forceinline__ uint4 pack8sum(const float* __restrict__ pa,
                                          const float* __restrict__ pb, float gs) {
  float4 a0 = *(const float4*)pa, a1 = *(const float4*)(pa + 4);
  float4 b0 = *(const float4*)pb, b1 = *(const float4*)(pb + 4);
  uint4 o;
  o.x = bf16rne((a0.x + b0.x) * gs) | (bf16rne((a0.y + b0.y) * gs) << 16);
  o.y = bf16rne((a0.z + b0.z) * gs) | (bf16rne((a0.w + b0.w) * gs) << 16);
  o.z = bf16rne((a1.x + b1.x) * gs) | (bf16rne((a1.y + b1.y) * gs) << 16);
  o.w = bf16rne((a1.z + b1.z) * gs) | (bf16rne((a1.w + b1.w) * gs) << 16);
  return o;
}
__device__ __forceinline__ v8s as_v8s(uint4 u) {
  union { uint4 u4; v8s s8; } cv; cv.u4 = u; return cv.s8;
}

// ---------------------------------------------------------------------------
// Merged prep, 49 blocks x 256. Block 48: deterministic compaction scan.
// ---------------------------------------------------------------------------
__global__ void prep_kernel(const float* __restrict__ Whh_a, const float* __restrict__ Whh_n,
                            const float* __restrict__ Wih_d, const float* __restrict__ Whh_d,
                            const float* __restrict__ bih_d, const float* __restrict__ bhh_d,
                            const int* __restrict__ cnts,
                            uint4* __restrict__ packA, uint4* __restrict__ packN,
                            uint4* __restrict__ packD, float* __restrict__ bd,
                            int* __restrict__ idxb) {
  const int b = blockIdx.x;
  if (b == 48) {
    // two-level inclusive scan of clamped counts; 256 thr x 8 entries.
    __shared__ int wsum[4];
    const int t = threadIdx.x, lane = t & 63, w = t >> 6;
    int c[8], tot = 0;
#pragma unroll
    for (int j = 0; j < 8; ++j) {
      int v = cnts[t * 8 + j];
      c[j] = v < 0 ? 0 : (v > NMAX ? NMAX : v);
      tot += c[j];
    }
    int inc = tot;
#pragma unroll
    for (int off = 1; off < 64; off <<= 1) {
      int v = __shfl_up(inc, off, 64);
      if (lane >= off) inc += v;
    }
    if (lane == 63) wsum[w] = inc;
    __syncthreads();
    int wbase = 0;
    for (int k = 0; k < w; ++k) wbase += wsum[k];
    int pos = wbase + inc - tot;  // exclusive prefix
#pragma unroll
    for (int j = 0; j < 8; ++j)
      for (int k = 0; k < c[j]; ++k) idxb[pos++] = (t * 8 + j) * NMAX + k;
    if (t == 0) {
      int Nv = wsum[0] + wsum[1] + wsum[2] + wsum[3];
      idxb[32768] = Nv;
      int end = (Nv + 31) & ~31;
      for (int i = Nv; i < end; ++i) idxb[i] = -1;  // tail block guard (32-pad)
    }
    return;
  }
  if (b < 16) {
    const int which = b >> 3;
    const float* Whh = which ? Whh_n : Whh_a;
    uint4* dst = which ? packN : packA;
    const int idx = (b & 7) * 256 + threadIdx.x;   // 0..2047
    const int lane = idx & 63, c = idx >> 6;       // c 0..31
    const int kh = c & 1, g = (c >> 1) & 3, w = c >> 3;
    const float gs = (g == 2) ? L2E2 : L2E;
    const int row = g * 64 + 16 * w + (lane & 15);
    const int kb = kh * 32 + (lane >> 4) * 8;
    dst[c * 64 + lane] = pack8(Whh + row * 64 + kb, gs);
  } else {
    const int idx = (b - 16) * 256 + threadIdx.x;  // 0..8191
    const int lane = idx & 63, c = idx >> 6;       // c 0..127
    const int kh = c & 3, i = (c >> 2) & 1, wv = c >> 3;
    const int g = wv & 3, q = wv >> 2;
    const float gs = (g == 2) ? L2E2 : L2E;
    const int ju = q * 32 + i * 16 + (lane & 15);
    const int row = g * 128 + ju;
    const int kb = kh * 32 + (lane >> 4) * 8;
    packD[c * 64 + lane] = pack8sum(Wih_d + row * 128 + kb, Whh_d + row * 128 + kb, gs);
    if (b < 18) {
      int iB = (b - 16) * 256 + threadIdx.x;       // 0..511
      float s = ((iB >> 7) == 2) ? L2E2 : L2E;
      bd[iB] = (bih_d[iB] + bhh_d[iB]) * s;
    }
  }
}

// ---------------------------------------------------------------------------
// Encoder R8. Blocks [0,1024) neighbour (compacted; dead tail exits),
// [1024,1088) agent; 256 thr = 4 waves; 32 seqs/block as TWO independent
// 16-seq groups. Per group: ping-pong hi-only h planes (16 rows x stride
// 72; group p at short-offset p*2304, buf b at +b*1152). 24 MFMA/step.
// ---------------------------------------------------------------------------
__global__ __launch_bounds__(256, 4) void enc_mfma_kernel(
    const float* __restrict__ xA, const float* __restrict__ xN,
    const v8s* __restrict__ packA, const v8s* __restrict__ packN,
    const float* __restrict__ Wih_a, const float* __restrict__ bih_a, const float* __restrict__ bhh_a,
    const float* __restrict__ Wih_n, const float* __restrict__ bih_n, const float* __restrict__ bhh_n,
    const int* __restrict__ idxb,
    float* __restrict__ outA, float* __restrict__ outN) {
  __shared__ unsigned short hph[4608];  // 2 groups x 2 ping-pong hi-planes
  __shared__ unsigned xbf[1600];        // [slot 0..31][t] bf16(x0)|bf16(x1)<<16
  __shared__ int sidx[32];
  const int tid = threadIdx.x, lane = tid & 63, wv = tid >> 6;
  const int nb = blockIdx.x;
  const bool isA = nb >= 1024;
  const int s0 = (isA ? nb - 1024 : nb) * 32;

  // dead neighbour blocks: everything past the compacted valid prefix
  if (!isA && s0 >= idxb[32768]) return;

  const float* xsrc = isA ? xA : xN;
  const v8s* pk = isA ? packA : packN;
  const float* Wih = isA ? Wih_a : Wih_n;
  const float* bih = isA ? bih_a : bih_n;
  const float* bhh = isA ? bhh_a : bhh_n;
  float* outp = isA ? outA : outN;

  // coalesced B-frag load (hi-only): chunk = wv*8+g*2+kh
  v8s B[4][2];
#pragma unroll
  for (int g = 0; g < 4; ++g)
#pragma unroll
    for (int kh = 0; kh < 2; ++kh)
      B[g][kh] = pk[(wv * 8 + g * 2 + kh) * 64 + lane];

  // B2[g]: x-projection fragment. Lanes ks==0 (lane<16): k-slot0 = wi0,
  // slot1 = wi1, slot2 = bias (all gs-scaled bf16); other lanes zero.
  v8s B2[4];
#pragma unroll
  for (int g = 0; g < 4; ++g) {
    uint4 u = {0u, 0u, 0u, 0u};
    if ((lane >> 4) == 0) {
      const float gs = (g == 2) ? L2E2 : L2E;
      const int ui = g * 64 + 16 * wv + (lane & 15);
      u.x = bf16rne(Wih[2 * ui] * gs) | (bf16rne(Wih[2 * ui + 1] * gs) << 16);
      u.y = bf16rne((bih[ui] + bhh[ui]) * gs);
    }
    B2[g] = as_v8s(u);
  }

  const int jc = lane & 15, qc = lane >> 4;  // C roles: unit col, seq quad
  const int c16 = 16 * wv + jc;

  // seq index table + zero both groups' buf0, then gather-stage x as bf16
  if (tid < 32) sidx[tid] = isA ? (s0 + tid) : idxb[s0 + tid];
  for (int i = tid; i < 1152; i += 256) {
    int j = (i < 576) ? i : i + 576;   // group0 buf0 dwords / group1 buf0
    ((unsigned*)hph)[j] = 0;
  }
  __syncthreads();  // sidx + hph-zero visible
  for (int i = tid; i < 800; i += 256) {
    int slot = i / 25, j = i - slot * 25;  // 25 float4 per seq, slot 0..31
    int sq = sidx[slot];
    float4 v = ((const float4*)(xsrc + (size_t)(sq < 0 ? 0 : sq) * 100))[j];
    xbf[slot * 50 + 2 * j]     = bf16rne(v.x) | (bf16rne(v.y) << 16);
    xbf[slot * 50 + 2 * j + 1] = bf16rne(v.z) | (bf16rne(v.w) << 16);
  }
  __syncthreads();

  const int ms = lane & 15, ks = lane >> 4;  // A roles: seq row, k-quad
  const v4f vzero = {0.f, 0.f, 0.f, 0.f};
  float cst0[4] = {0.f, 0.f, 0.f, 0.f};
  float cst1[4] = {0.f, 0.f, 0.f, 0.f};

  auto enc_step = [&](int t, int rb, int wb) {
    // A2 per group (lanes ks==0: bf16(x0),bf16(x1),1.0; rest zero)
    uint4 a2u0, a2u1;
    a2u0.x = (ks == 0) ? xbf[ms * 50 + t] : 0u;
    a2u1.x = (ks == 0) ? xbf[(16 + ms) * 50 + t] : 0u;
    a2u0.y = a2u1.y = (ks == 0) ? 0x3f80u : 0u;  // bf16(1.0) in slot 2
    a2u0.z = a2u0.w = a2u1.z = a2u1.w = 0u;
    v8s A20 = as_v8s(a2u0), A21 = as_v8s(a2u1);

    v4f a40[4], a41[4];
#pragma unroll
    for (int g = 0; g < 4; ++g) {
      a40[g] = mfma16(A20, B2[g], vzero);   // wi0*x0 + wi1*x1 + bias
      a41[g] = mfma16(A21, B2[g], vzero);
    }

    // h @ Whh^T, A hi-only: 8 MFMA per group, interleaved
#pragma unroll
    for (int kh = 0; kh < 2; ++kh) {
      v8s Ahi0 = *(const __shared__ v8s*)&hph[rb + ms * 72 + kh * 32 + ks * 8];
      v8s Ahi1 = *(const __shared__ v8s*)&hph[2304 + rb + ms * 72 + kh * 32 + ks * 8];
#pragma unroll
      for (int g = 0; g < 4; ++g) {
        a40[g] = mfma16(Ahi0, B[g][kh], a40[g]);
        a41[g] = mfma16(Ahi1, B[g][kh], a41[g]);
      }
    }

    // pointwise (two independent chains) + RNE bf16 h-store
#pragma unroll
    for (int r = 0; r < 4; ++r) {
      float h0 = cell_update(a40[0][r], a40[1][r], a40[2][r], a40[3][r], cst0[r]);
      float h1 = cell_update(a41[0][r], a41[1][r], a41[2][r], a41[3][r], cst1[r]);
      hph[wb + (qc * 4 + r) * 72 + c16] = (unsigned short)bf16rne(h0);
      hph[2304 + wb + (qc * 4 + r) * 72 + c16] = (unsigned short)bf16rne(h1);
    }
    __syncthreads();
  };

  for (int t2 = 0; t2 < T_SEQ; t2 += 2) {
    enc_step(t2 + 0, 0, 1152);
    enc_step(t2 + 1, 1152, 0);
  }

  // final h in buf0 of each group; widen bf16 -> fp32 (R5/R7-verified
  // bit-identical: dec staging RNE-rounds h0; rne idempotent, monotone).
#pragma unroll
  for (int r = 0; r < 4; ++r) {
    int row = qc * 4 + r;
    int sq0 = sidx[row];
    if (sq0 >= 0) {
      unsigned hs = hph[row * 72 + c16];
      outp[(size_t)sq0 * 64 + c16] = __uint_as_float(hs << 16);
    }
    int sq1 = sidx[16 + row];
    if (sq1 >= 0) {
      unsigned hs = hph[2304 + row * 72 + c16];
      outp[(size_t)sq1 * 64 + c16] = __uint_as_float(hs << 16);
    }
  }
}

// ---------------------------------------------------------------------------
// Decoder v8. 256 blocks x 512 thr (8 waves), 8 seqs/block.
// Wave wv owns units [wv*16, wv*16+16) and ALL 4 gates: 16 MFMA/step.
// Cell update fully in-register; ping-pong hph -> ONE barrier per step.
// Pred partials -> pall, combined once at the end.
// ---------------------------------------------------------------------------
__global__ __launch_bounds__(512, 2) void dec_mfma_kernel(
    const v8s* __restrict__ pkd, const float* __restrict__ bd,
    const float* __restrict__ aemb, const float* __restrict__ nenc,
    const int* __restrict__ cnts, const float* __restrict__ Wpos,
    const float* __restrict__ bpos, float* __restrict__ out) {
  __shared__ unsigned short hph[2][2176];  // 16 rows x stride 136, ping-pong
  __shared__ float pall[3840];             // [t][wv][s][c] = t*128+wv*16+s*2+c
  const int tid = threadIdx.x, lane = tid & 63, wv = tid >> 6;  // wv 0..7
  const int jc = lane & 15, qc = lane >> 4;
  const int s0 = blockIdx.x * 8;

  // B-frags: gate g, unit tile wv, k-half kh (prep chunk layout).
  v8s B[4][4];
  float bs[4];
#pragma unroll
  for (int g = 0; g < 4; ++g) {
#pragma unroll
    for (int kh = 0; kh < 4; ++kh)
      B[g][kh] = pkd[(((wv >> 1) * 4 + g) * 8 + (wv & 1) * 4 + kh) * 64 + lane];
    bs[g] = bd[g * 128 + wv * 16 + jc];
  }
  const float wp0 = Wpos[wv * 16 + jc];
  const float wp1 = Wpos[128 + wv * 16 + jc];
  const float bp0 = bpos[0], bp1 = bpos[1];

  // zero both hph buffers (rows 8..15 stay zero forever)
  for (int i = tid; i < 2176; i += 512) ((unsigned*)hph)[i] = 0;
  __syncthreads();

  // stage h0 rows 0..7 into buf0 (fused hmax; only cnt neighbour rows read)
  for (int i = tid; i < 1024; i += 512) {
    int row = i >> 7, unit = i & 127;
    float v;
    if (unit < 64) {
      v = aemb[(size_t)(s0 + row) * 64 + unit];
    } else {
      int cnt = cnts[s0 + row];
      cnt = cnt < 0 ? 0 : (cnt > NMAX ? NMAX : cnt);
      float m = -1e30f;
      for (int n = 0; n < cnt; ++n)
        m = fmaxf(m, nenc[((size_t)((s0 + row) * NMAX + n)) * 64 + (unit - 64)]);
      v = (cnt > 0) ? m : 0.f;
    }
    hph[0][row * 136 + unit] = (unsigned short)bf16rne(v);
  }
  float cst[4] = {0.f, 0.f, 0.f, 0.f};
  __syncthreads();

  for (int t = 0; t < PRED_STEPS; ++t) {
    const int rb = t & 1, wb = rb ^ 1;
    v4f acc[4];
#pragma unroll
    for (int g = 0; g < 4; ++g)
      acc[g] = (v4f){bs[g], bs[g], bs[g], bs[g]};
#pragma unroll
    for (int kh = 0; kh < 4; ++kh) {
      v8s Ahi = *(const __shared__ v8s*)&hph[rb][jc * 136 + kh * 32 + qc * 8];
#pragma unroll
      for (int g = 0; g < 4; ++g)
        acc[g] = mfma16(Ahi, B[g][kh], acc[g]);
    }

    // in-register cell: rows qc*4+r; valid seqs are qc<2 (rows 8..15 are
    // zero-h -> bias-only gates, finite garbage, never stored)
    float hr[4];
#pragma unroll
    for (int r = 0; r < 4; ++r)
      hr[r] = cell_update(acc[0][r], acc[1][r], acc[2][r], acc[3][r], cst[r]);

    if (qc < 2) {
#pragma unroll
      for (int r = 0; r < 4; ++r)
        hph[wb][(qc * 4 + r) * 136 + wv * 16 + jc] =
            (unsigned short)bf16rne(hr[r]);
    }

    // pred partials: reduce over jc (16 lanes) within each qc group
    float pr0[4], pr1[4];
#pragma unroll
    for (int r = 0; r < 4; ++r) { pr0[r] = hr[r] * wp0; pr1[r] = hr[r] * wp1; }
#pragma unroll
    for (int off = 1; off < 16; off <<= 1) {
#pragma unroll
      for (int r = 0; r < 4; ++r) {
        pr0[r] += __shfl_xor(pr0[r], off, 64);
        pr1[r] += __shfl_xor(pr1[r], off, 64);
      }
    }
    if (jc == 0 && qc < 2) {
#pragma unroll
      for (int r = 0; r < 4; ++r) {
        int s = qc * 4 + r;
        pall[t * 128 + wv * 16 + s * 2 + 0] = pr0[r];
        pall[t * 128 + wv * 16 + s * 2 + 1] = pr1[r];
      }
    }
    __syncthreads();  // single barrier: hph[wb] + (eventually) pall visible
  }

  // combine pred partials: 480 outputs, sum over 8 waves
  if (tid < 480) {
    int s = tid / 60, r60 = tid - s * 60;
    int t = r60 >> 1, c = r60 & 1;
    float a = c ? bp1 : bp0;
#pragma unroll
    for (int w = 0; w < 8; ++w)
      a += pall[t * 128 + w * 16 + s * 2 + c];
    out[(size_t)(s0 + s) * 60 + r60] = a;
  }
}

extern "C" void kernel_launch(void* const* d_in, const int* in_sizes, int n_in,
                              void* d_out, int out_size, void* d_ws, size_t ws_size,
                              hipStream_t stream) {
  (void)in_sizes; (void)n_in; (void)out_size; (void)ws_size;
  const float* xA    = (const float*)d_in[0];
  const float* xN    = (const float*)d_in[1];
  const int*   cnts  = (const int*)d_in[2];
  const float* Wih_a = (const float*)d_in[3];
  const float* Whh_a = (const float*)d_in[4];
  const float* bih_a = (const float*)d_in[5];
  const float* bhh_a = (const float*)d_in[6];
  const float* Wih_n = (const float*)d_in[7];
  const float* Whh_n = (const float*)d_in[8];
  const float* bih_n = (const float*)d_in[9];
  const float* bhh_n = (const float*)d_in[10];
  const float* Wih_d = (const float*)d_in[11];
  const float* Whh_d = (const float*)d_in[12];
  const float* bih_d = (const float*)d_in[13];
  const float* bhh_d = (const float*)d_in[14];
  const float* Wpos  = (const float*)d_in[15];
  const float* bpos  = (const float*)d_in[16];
  float* out = (float*)d_out;
  float* wsf = (float*)d_ws;
  int* idxb = (int*)(wsf + OFF_IDX);

  prep_kernel<<<49, 256, 0, stream>>>(Whh_a, Whh_n, Wih_d, Whh_d, bih_d, bhh_d,
                                      cnts,
                                      (uint4*)(wsf + OFF_PACKA),
                                      (uint4*)(wsf + OFF_PACKN),
                                      (uint4*)(wsf + OFF_WDP), wsf + OFF_WDB,
                                      idxb);
  enc_mfma_kernel<<<1088, 256, 0, stream>>>(
      xA, xN,
      (const v8s*)(wsf + OFF_PACKA), (const v8s*)(wsf + OFF_PACKN),
      Wih_a, bih_a, bhh_a, Wih_n, bih_n, bhh_n, idxb,
      wsf + OFF_AEMB, wsf + OFF_NENC);
  dec_mfma_kernel<<<256, 512, 0, stream>>>(
      (const v8s*)(wsf + OFF_WDP), wsf + OFF_WDB,
      wsf + OFF_AEMB, wsf + OFF_NENC, cnts,
      Wpos, bpos, out);
}

// Round 10
// 220.825 us; speedup vs baseline: 1.4728x; 1.1129x over previous
//
#include <hip/hip_runtime.h>
#include <stdint.h>

// ---------------------------------------------------------------------------
// Social LSTM model, bf16 MFMA: A hi-only (RNE), B hi-only (RNE).
// R10: REVERT to R6 (measured optimum: enc 87us / VGPR 44 / total 222).
// Closed investigation ledger:
//   - occupancy via launch_bounds >4 w/SIMD: spills (R3/R5/R7, 3 probes)
//   - 2-group ILP (R8): 1.48x REGRESSION -- 640 live blocks = 2.5 w/SIMD
//     resident; TLP loss > ILP gain. Law: keep >=4 resident waves/SIMD;
//     4 is both the register cap and the block-granularity optimum.
//   - x-proj folded into MFMA K-extension (R6): KEPT (-20% VALU, VGPR 64->44)
//   - valid-neighbour compaction (R1): KEPT (~2x less enc work)
//   - dec in-register cell, 1 barrier/step (R2): KEPT
//   - self-pack / launch-count reduction (R4): slower, reverted
// enc floor analysis: VALUBusy 59% + MfmaUtil 21% ~= 80% issue; remainder
// is recurrence latency at the 4-wave/SIMD cap -- structural.
// Residual ~115us of total is harness reset/launch overhead.
// ---------------------------------------------------------------------------

#define T_SEQ 50
#define PRED_STEPS 30
#define NMAX 16

typedef float v2f __attribute__((ext_vector_type(2)));
typedef float v4f __attribute__((ext_vector_type(4)));
typedef short v8s __attribute__((ext_vector_type(8)));

#define L2E 1.44269504f
#define L2E2 2.88539008f

// ws layout (float offsets)
static constexpr size_t OFF_AEMB  = 0;          // 2048*64
static constexpr size_t OFF_NENC  = 131072;     // 32768*64
static constexpr size_t OFF_IDX   = 2228224;    // 32768 ints + 1 counter
static constexpr size_t OFF_PACKA = 2490368;    // 8192 floats (32 KB pack)
static constexpr size_t OFF_PACKN = 2498560;    // 8192 floats
static constexpr size_t OFF_WDP   = 2506752;    // 32768 floats (128 KB pack)
static constexpr size_t OFF_WDB   = 2539520;    // 512 floats fused dec bias

__device__ __forceinline__ float frcp(float x) { return __builtin_amdgcn_rcpf(x); }
#if __has_builtin(__builtin_amdgcn_exp2f)
__device__ __forceinline__ float fexp2(float x) { return __builtin_amdgcn_exp2f(x); }
#else
__device__ __forceinline__ float fexp2(float x) { return exp2f(x); }
#endif
__device__ __forceinline__ unsigned bf16rne(float f) {
  unsigned u = __float_as_uint(f);
  u += 0x7fff + ((u >> 16) & 1);
  return u >> 16;
}
__device__ __forceinline__ v4f mfma16(v8s a, v8s b, v4f c) {
  return __builtin_amdgcn_mfma_f32_16x16x32_bf16(a, b, c, 0, 0, 0);
}

// Shared-rcp LSTM cell. Gates PRE-SCALED: i,f,o by log2e; g by 2*log2e.
__device__ __forceinline__ float cell_update(float iv, float fv, float gv,
                                             float ov, float& cref) {
  float ef = fexp2(-fv);
  float ei = fexp2(-iv);
  float eg = fexp2(-gv);
  float t1 = (1.f + ei) * (1.f + eg);
  float rD = frcp((1.f + ef) * t1);
  float sf = t1 * rD;
  float u  = (1.f - eg) * ((1.f + ef) * rD);
  float cn = fmaf(sf, cref, u);
  cref = cn;
  float eo = fexp2(-ov);
  float ec = fexp2(fminf(-L2E2 * cn, 60.f));
  return (1.f - ec) * frcp((1.f + eo) * (1.f + ec));
}

// pack 8 consecutive scaled floats -> hi-only RNE bf16x8 (one uint4)
__device__ __forceinline__ uint4 pack8(const float* __restrict__ p, float gs) {
  float4 w0 = *(const float4*)p;
  float4 w1 = *(const float4*)(p + 4);
  uint4 o;
  o.x = bf16rne(w0.x * gs) | (bf16rne(w0.y * gs) << 16);
  o.y = bf16rne(w0.z * gs) | (bf16rne(w0.w * gs) << 16);
  o.z = bf16rne(w1.x * gs) | (bf16rne(w1.y * gs) << 16);
  o.w = bf16rne(w1.z * gs) | (bf16rne(w1.w * gs) << 16);
  return o;
}
__device__ __forceinline__ uint4 pack8sum(const float* __restrict__ pa,
                                          const float* __restrict__ pb, float gs) {
  float4 a0 = *(const float4*)pa, a1 = *(const float4*)(pa + 4);
  float4 b0 = *(const float4*)pb, b1 = *(const float4*)(pb + 4);
  uint4 o;
  o.x = bf16rne((a0.x + b0.x) * gs) | (bf16rne((a0.y + b0.y) * gs) << 16);
  o.y = bf16rne((a0.z + b0.z) * gs) | (bf16rne((a0.w + b0.w) * gs) << 16);
  o.z = bf16rne((a1.x + b1.x) * gs) | (bf16rne((a1.y + b1.y) * gs) << 16);
  o.w = bf16rne((a1.z + b1.z) * gs) | (bf16rne((a1.w + b1.w) * gs) << 16);
  return o;
}
__device__ __forceinline__ v8s as_v8s(uint4 u) {
  union { uint4 u4; v8s s8; } cv; cv.u4 = u; return cv.s8;
}

// ---------------------------------------------------------------------------
// Merged prep, 49 blocks x 256. Block 48: deterministic compaction scan.
// ---------------------------------------------------------------------------
__global__ void prep_kernel(const float* __restrict__ Whh_a, const float* __restrict__ Whh_n,
                            const float* __restrict__ Wih_d, const float* __restrict__ Whh_d,
                            const float* __restrict__ bih_d, const float* __restrict__ bhh_d,
                            const int* __restrict__ cnts,
                            uint4* __restrict__ packA, uint4* __restrict__ packN,
                            uint4* __restrict__ packD, float* __restrict__ bd,
                            int* __restrict__ idxb) {
  const int b = blockIdx.x;
  if (b == 48) {
    // two-level inclusive scan of clamped counts; 256 thr x 8 entries.
    __shared__ int wsum[4];
    const int t = threadIdx.x, lane = t & 63, w = t >> 6;
    int c[8], tot = 0;
#pragma unroll
    for (int j = 0; j < 8; ++j) {
      int v = cnts[t * 8 + j];
      c[j] = v < 0 ? 0 : (v > NMAX ? NMAX : v);
      tot += c[j];
    }
    int inc = tot;
#pragma unroll
    for (int off = 1; off < 64; off <<= 1) {
      int v = __shfl_up(inc, off, 64);
      if (lane >= off) inc += v;
    }
    if (lane == 63) wsum[w] = inc;
    __syncthreads();
    int wbase = 0;
    for (int k = 0; k < w; ++k) wbase += wsum[k];
    int pos = wbase + inc - tot;  // exclusive prefix
#pragma unroll
    for (int j = 0; j < 8; ++j)
      for (int k = 0; k < c[j]; ++k) idxb[pos++] = (t * 8 + j) * NMAX + k;
    if (t == 0) {
      int Nv = wsum[0] + wsum[1] + wsum[2] + wsum[3];
      idxb[32768] = Nv;
      int end = (Nv + 15) & ~15;
      for (int i = Nv; i < end; ++i) idxb[i] = -1;  // tail block guard
    }
    return;
  }
  if (b < 16) {
    const int which = b >> 3;
    const float* Whh = which ? Whh_n : Whh_a;
    uint4* dst = which ? packN : packA;
    const int idx = (b & 7) * 256 + threadIdx.x;   // 0..2047
    const int lane = idx & 63, c = idx >> 6;       // c 0..31
    const int kh = c & 1, g = (c >> 1) & 3, w = c >> 3;
    const float gs = (g == 2) ? L2E2 : L2E;
    const int row = g * 64 + 16 * w + (lane & 15);
    const int kb = kh * 32 + (lane >> 4) * 8;
    dst[c * 64 + lane] = pack8(Whh + row * 64 + kb, gs);
  } else {
    const int idx = (b - 16) * 256 + threadIdx.x;  // 0..8191
    const int lane = idx & 63, c = idx >> 6;       // c 0..127
    const int kh = c & 3, i = (c >> 2) & 1, wv = c >> 3;
    const int g = wv & 3, q = wv >> 2;
    const float gs = (g == 2) ? L2E2 : L2E;
    const int ju = q * 32 + i * 16 + (lane & 15);
    const int row = g * 128 + ju;
    const int kb = kh * 32 + (lane >> 4) * 8;
    packD[c * 64 + lane] = pack8sum(Wih_d + row * 128 + kb, Whh_d + row * 128 + kb, gs);
    if (b < 18) {
      int iB = (b - 16) * 256 + threadIdx.x;       // 0..511
      float s = ((iB >> 7) == 2) ? L2E2 : L2E;
      bd[iB] = (bih_d[iB] + bhh_d[iB]) * s;
    }
  }
}

// ---------------------------------------------------------------------------
// Encoder. Blocks [0,2048) neighbour (compacted; dead tail exits),
// [2048,2176) agent; 256 thr = 4 waves. Ping-pong h planes (halfwords,
// HI-ONLY): buf b at base b*1152; row stride 72.
// 12 MFMA/step: x-projection rides a K-extension block (lanes ks==0 carry
// bf16(x0),bf16(x1),1.0; B2[g] carries bf16(wi0,wi1,bias), gs-folded).
// ---------------------------------------------------------------------------
__global__ __launch_bounds__(256, 4) void enc_mfma_kernel(
    const float* __restrict__ xA, const float* __restrict__ xN,
    const v8s* __restrict__ packA, const v8s* __restrict__ packN,
    const float* __restrict__ Wih_a, const float* __restrict__ bih_a, const float* __restrict__ bhh_a,
    const float* __restrict__ Wih_n, const float* __restrict__ bih_n, const float* __restrict__ bhh_n,
    const int* __restrict__ idxb,
    float* __restrict__ outA, float* __restrict__ outN) {
  __shared__ unsigned short hph[2304];  // 2 ping-pong hi-planes
  __shared__ unsigned xbf[800];         // [seq][t] bf16(x0)|bf16(x1)<<16
  __shared__ int sidx[16];
  const int tid = threadIdx.x, lane = tid & 63, wv = tid >> 6;
  const int nb = blockIdx.x;
  const bool isA = nb >= 2048;
  const int s0 = (isA ? nb - 2048 : nb) * 16;

  // dead neighbour blocks: everything past the compacted valid prefix
  if (!isA && s0 >= idxb[32768]) return;

  const float* xsrc = isA ? xA : xN;
  const v8s* pk = isA ? packA : packN;
  const float* Wih = isA ? Wih_a : Wih_n;
  const float* bih = isA ? bih_a : bih_n;
  const float* bhh = isA ? bhh_a : bhh_n;
  float* outp = isA ? outA : outN;

  // coalesced B-frag load (hi-only): chunk = wv*8+g*2+kh
  v8s B[4][2];
#pragma unroll
  for (int g = 0; g < 4; ++g)
#pragma unroll
    for (int kh = 0; kh < 2; ++kh)
      B[g][kh] = pk[(wv * 8 + g * 2 + kh) * 64 + lane];

  // B2[g]: x-projection fragment. Lanes ks==0 (lane<16): k-slot0 = wi0,
  // slot1 = wi1, slot2 = bias (all gs-scaled bf16); other lanes zero.
  v8s B2[4];
#pragma unroll
  for (int g = 0; g < 4; ++g) {
    uint4 u = {0u, 0u, 0u, 0u};
    if ((lane >> 4) == 0) {
      const float gs = (g == 2) ? L2E2 : L2E;
      const int ui = g * 64 + 16 * wv + (lane & 15);
      u.x = bf16rne(Wih[2 * ui] * gs) | (bf16rne(Wih[2 * ui + 1] * gs) << 16);
      u.y = bf16rne((bih[ui] + bhh[ui]) * gs);
    }
    B2[g] = as_v8s(u);
  }

  const int jc = lane & 15, qc = lane >> 4;  // C roles: unit col, seq quad

  // seq index table + zero buf0, then gather-stage x as bf16 pairs
  if (tid < 16) sidx[tid] = isA ? (s0 + tid) : idxb[s0 + tid];
  for (int i = tid; i < 576; i += 256) ((unsigned*)hph)[i] = 0;
  __syncthreads();  // sidx + hph-zero visible
  for (int i = tid; i < 400; i += 256) {
    int slot = i / 25, j = i - slot * 25;  // 25 float4 per seq
    int sq = sidx[slot];
    float4 v = ((const float4*)(xsrc + (size_t)(sq < 0 ? 0 : sq) * 100))[j];
    xbf[slot * 50 + 2 * j]     = bf16rne(v.x) | (bf16rne(v.y) << 16);
    xbf[slot * 50 + 2 * j + 1] = bf16rne(v.z) | (bf16rne(v.w) << 16);
  }
  __syncthreads();

  const int ms = lane & 15, ks = lane >> 4;  // A roles: seq row, k-quad
  const v4f vzero = {0.f, 0.f, 0.f, 0.f};
  float cst[4] = {0.f, 0.f, 0.f, 0.f};
  float h[4];

  auto enc_step = [&](int t, int rb, int wb) {
    // A2: x-block (lanes ks==0: bf16(x0),bf16(x1),1.0; rest zero)
    uint4 a2u;
    a2u.x = (ks == 0) ? xbf[ms * 50 + t] : 0u;
    a2u.y = (ks == 0) ? 0x3f80u : 0u;   // bf16(1.0) in slot 2
    a2u.z = 0u; a2u.w = 0u;
    v8s A2 = as_v8s(a2u);

    v4f a4[4];
#pragma unroll
    for (int g = 0; g < 4; ++g)
      a4[g] = mfma16(A2, B2[g], vzero);   // wi0*x0 + wi1*x1 + bias

    // h @ Whh^T, A hi-only: 8 MFMA
#pragma unroll
    for (int kh = 0; kh < 2; ++kh) {
      v8s Ahi = *(const __shared__ v8s*)&hph[rb + ms * 72 + kh * 32 + ks * 8];
#pragma unroll
      for (int g = 0; g < 4; ++g)
        a4[g] = mfma16(Ahi, B[g][kh], a4[g]);
    }

    // pointwise + RNE bf16 h-store into the OTHER buffer
#pragma unroll
    for (int r = 0; r < 4; ++r) {
      h[r] = cell_update(a4[0][r], a4[1][r], a4[2][r], a4[3][r], cst[r]);
      hph[wb + (qc * 4 + r) * 72 + 16 * wv + jc] =
          (unsigned short)bf16rne(h[r]);
    }
    __syncthreads();
  };

  for (int t2 = 0; t2 < T_SEQ; t2 += 2) {
    enc_step(t2 + 0, 0, 1152);
    enc_step(t2 + 1, 1152, 0);
  }

#pragma unroll
  for (int r = 0; r < 4; ++r) {
    int sq = sidx[qc * 4 + r];
    if (sq >= 0)
      outp[(size_t)sq * 64 + 16 * wv + jc] = h[r];
  }
}

// ---------------------------------------------------------------------------
// Decoder v8. 256 blocks x 512 thr (8 waves), 8 seqs/block.
// Wave wv owns units [wv*16, wv*16+16) and ALL 4 gates: 16 MFMA/step.
// Cell update fully in-register; ping-pong hph -> ONE barrier per step.
// Pred partials -> pall, combined once at the end.
// ---------------------------------------------------------------------------
__global__ __launch_bounds__(512, 2) void dec_mfma_kernel(
    const v8s* __restrict__ pkd, const float* __restrict__ bd,
    const float* __restrict__ aemb, const float* __restrict__ nenc,
    const int* __restrict__ cnts, const float* __restrict__ Wpos,
    const float* __restrict__ bpos, float* __restrict__ out) {
  __shared__ unsigned short hph[2][2176];  // 16 rows x stride 136, ping-pong
  __shared__ float pall[3840];             // [t][wv][s][c] = t*128+wv*16+s*2+c
  const int tid = threadIdx.x, lane = tid & 63, wv = tid >> 6;  // wv 0..7
  const int jc = lane & 15, qc = lane >> 4;
  const int s0 = blockIdx.x * 8;

  // B-frags: gate g, unit tile wv, k-half kh (prep chunk layout).
  v8s B[4][4];
  float bs[4];
#pragma unroll
  for (int g = 0; g < 4; ++g) {
#pragma unroll
    for (int kh = 0; kh < 4; ++kh)
      B[g][kh] = pkd[(((wv >> 1) * 4 + g) * 8 + (wv & 1) * 4 + kh) * 64 + lane];
    bs[g] = bd[g * 128 + wv * 16 + jc];
  }
  const float wp0 = Wpos[wv * 16 + jc];
  const float wp1 = Wpos[128 + wv * 16 + jc];
  const float bp0 = bpos[0], bp1 = bpos[1];

  // zero both hph buffers (rows 8..15 stay zero forever)
  for (int i = tid; i < 2176; i += 512) ((unsigned*)hph)[i] = 0;
  __syncthreads();

  // stage h0 rows 0..7 into buf0 (fused hmax; only cnt neighbour rows read)
  for (int i = tid; i < 1024; i += 512) {
    int row = i >> 7, unit = i & 127;
    float v;
    if (unit < 64) {
      v = aemb[(size_t)(s0 + row) * 64 + unit];
    } else {
      int cnt = cnts[s0 + row];
      cnt = cnt < 0 ? 0 : (cnt > NMAX ? NMAX : cnt);
      float m = -1e30f;
      for (int n = 0; n < cnt; ++n)
        m = fmaxf(m, nenc[((size_t)((s0 + row) * NMAX + n)) * 64 + (unit - 64)]);
      v = (cnt > 0) ? m : 0.f;
    }
    hph[0][row * 136 + unit] = (unsigned short)bf16rne(v);
  }
  float cst[4] = {0.f, 0.f, 0.f, 0.f};
  __syncthreads();

  for (int t = 0; t < PRED_STEPS; ++t) {
    const int rb = t & 1, wb = rb ^ 1;
    v4f acc[4];
#pragma unroll
    for (int g = 0; g < 4; ++g)
      acc[g] = (v4f){bs[g], bs[g], bs[g], bs[g]};
#pragma unroll
    for (int kh = 0; kh < 4; ++kh) {
      v8s Ahi = *(const __shared__ v8s*)&hph[rb][jc * 136 + kh * 32 + qc * 8];
#pragma unroll
      for (int g = 0; g < 4; ++g)
        acc[g] = mfma16(Ahi, B[g][kh], acc[g]);
    }

    // in-register cell: rows qc*4+r; valid seqs are qc<2 (rows 8..15 are
    // zero-h -> bias-only gates, finite garbage, never stored)
    float hr[4];
#pragma unroll
    for (int r = 0; r < 4; ++r)
      hr[r] = cell_update(acc[0][r], acc[1][r], acc[2][r], acc[3][r], cst[r]);

    if (qc < 2) {
#pragma unroll
      for (int r = 0; r < 4; ++r)
        hph[wb][(qc * 4 + r) * 136 + wv * 16 + jc] =
            (unsigned short)bf16rne(hr[r]);
    }

    // pred partials: reduce over jc (16 lanes) within each qc group
    float pr0[4], pr1[4];
#pragma unroll
    for (int r = 0; r < 4; ++r) { pr0[r] = hr[r] * wp0; pr1[r] = hr[r] * wp1; }
#pragma unroll
    for (int off = 1; off < 16; off <<= 1) {
#pragma unroll
      for (int r = 0; r < 4; ++r) {
        pr0[r] += __shfl_xor(pr0[r], off, 64);
        pr1[r] += __shfl_xor(pr1[r], off, 64);
      }
    }
    if (jc == 0 && qc < 2) {
#pragma unroll
      for (int r = 0; r < 4; ++r) {
        int s = qc * 4 + r;
        pall[t * 128 + wv * 16 + s * 2 + 0] = pr0[r];
        pall[t * 128 + wv * 16 + s * 2 + 1] = pr1[r];
      }
    }
    __syncthreads();  // single barrier: hph[wb] + (eventually) pall visible
  }

  // combine pred partials: 480 outputs, sum over 8 waves
  if (tid < 480) {
    int s = tid / 60, r60 = tid - s * 60;
    int t = r60 >> 1, c = r60 & 1;
    float a = c ? bp1 : bp0;
#pragma unroll
    for (int w = 0; w < 8; ++w)
      a += pall[t * 128 + w * 16 + s * 2 + c];
    out[(size_t)(s0 + s) * 60 + r60] = a;
  }
}

extern "C" void kernel_launch(void* const* d_in, const int* in_sizes, int n_in,
                              void* d_out, int out_size, void* d_ws, size_t ws_size,
                              hipStream_t stream) {
  (void)in_sizes; (void)n_in; (void)out_size; (void)ws_size;
  const float* xA    = (const float*)d_in[0];
  const float* xN    = (const float*)d_in[1];
  const int*   cnts  = (const int*)d_in[2];
  const float* Wih_a = (const float*)d_in[3];
  const float* Whh_a = (const float*)d_in[4];
  const float* bih_a = (const float*)d_in[5];
  const float* bhh_a = (const float*)d_in[6];
  const float* Wih_n = (const float*)d_in[7];
  const float* Whh_n = (const float*)d_in[8];
  const float* bih_n = (const float*)d_in[9];
  const float* bhh_n = (const float*)d_in[10];
  const float* Wih_d = (const float*)d_in[11];
  const float* Whh_d = (const float*)d_in[12];
  const float* bih_d = (const float*)d_in[13];
  const float* bhh_d = (const float*)d_in[14];
  const float* Wpos  = (const float*)d_in[15];
  const float* bpos  = (const float*)d_in[16];
  float* out = (float*)d_out;
  float* wsf = (float*)d_ws;
  int* idxb = (int*)(wsf + OFF_IDX);

  prep_kernel<<<49, 256, 0, stream>>>(Whh_a, Whh_n, Wih_d, Whh_d, bih_d, bhh_d,
                                      cnts,
                                      (uint4*)(wsf + OFF_PACKA),
                                      (uint4*)(wsf + OFF_PACKN),
                                      (uint4*)(wsf + OFF_WDP), wsf + OFF_WDB,
                                      idxb);
  enc_mfma_kernel<<<2176, 256, 0, stream>>>(
      xA, xN,
      (const v8s*)(wsf + OFF_PACKA), (const v8s*)(wsf + OFF_PACKN),
      Wih_a, bih_a, bhh_a, Wih_n, bih_n, bhh_n, idxb,
      wsf + OFF_AEMB, wsf + OFF_NENC);
  dec_mfma_kernel<<<256, 512, 0, stream>>>(
      (const v8s*)(wsf + OFF_WDP), wsf + OFF_WDB,
      wsf + OFF_AEMB, wsf + OFF_NENC, cnts,
      Wpos, bpos, out);
}